// Round 1
// baseline (4655.867 us; speedup 1.0000x reference)
//
#include <hip/hip_runtime.h>
#include <stdint.h>

// ---------------------------------------------------------------------------
// MyRNN on MI355X (gfx950).
// Dims: BATCH=512, SEQ=256, X_DIM=512, H_DIM=1024.
// Plan:
//   1) cvt X, W_hh, W_xh to bf16 in ws.
//   2) v = W_hh^T @ W_hy in fp32 (folds final linear step + output dot).
//   3) Xp[t][b][j] = X@W_xh^T + bias  (one big bf16 MFMA GEMM, M=131072,K=512).
//   4) H1 = sigmoid(Xp_0)  (H0 = 0).
//   5) 254 step GEMMs: H_{t+1} = sigmoid(H_t @ W_hh^T + Xp_t), bf16 MFMA.
//   6) out[b] = H_255 . v + Xp_255 . W_hy   (fp32).
// ---------------------------------------------------------------------------

typedef unsigned short u16;
typedef __attribute__((ext_vector_type(8))) __bf16 bf16x8;  // 4 VGPRs = MFMA A/B frag
typedef __attribute__((ext_vector_type(4))) float f32x4;    // MFMA C/D frag

#define BATCH 512
#define SEQ 256
#define XD 512
#define HD 1024

__device__ __forceinline__ float bf2f(u16 u) {
  unsigned int x = ((unsigned int)u) << 16;
  float f;
  __builtin_memcpy(&f, &x, 4);
  return f;
}
__device__ __forceinline__ u16 f2bf(float f) {
  unsigned int x;
  __builtin_memcpy(&x, &f, 4);
  x = (x + 0x7FFFu + ((x >> 16) & 1u)) >> 16;  // round-to-nearest-even
  return (u16)x;
}
__device__ __forceinline__ void g2lds16(const void* g, void* l) {
  // async global->LDS, 16B/lane, LDS dst = wave-uniform base + lane*16
  __builtin_amdgcn_global_load_lds(
      (const __attribute__((address_space(1))) unsigned int*)g,
      (__attribute__((address_space(3))) unsigned int*)l, 16, 0, 0);
}
__device__ __forceinline__ float sigmoidf(float x) {
  return 1.0f / (1.0f + __expf(-x));
}

// --------------------------- elementwise fp32 -> bf16 ----------------------
__global__ void k_cvt(const float* __restrict__ src, u16* __restrict__ dst, int n4) {
  int i = blockIdx.x * blockDim.x + threadIdx.x;
  if (i < n4) {
    float4 f = ((const float4*)src)[i];
    ushort4 u;
    u.x = f2bf(f.x); u.y = f2bf(f.y); u.z = f2bf(f.z); u.w = f2bf(f.w);
    ((ushort4*)dst)[i] = u;
  }
}

// --------------------------- v[k] = sum_j W_hy[j]*W_hh[j][k] (fp32) --------
__global__ void k_v(const float* __restrict__ whh, const float* __restrict__ why,
                    float* __restrict__ v) {
  int k = blockIdx.x * 256 + threadIdx.x;  // gridDim.x = 4
  int j0 = blockIdx.y * 128;               // gridDim.y = 8
  float s = 0.f;
  for (int j = j0; j < j0 + 128; ++j) s += why[j] * whh[j * HD + k];
  atomicAdd(&v[k], s);
}

// --------------------------- Xp GEMM ---------------------------------------
// C[r=(b,t)][j] = sum_k Xbf[r][k]*Wxh[j][k] + bias[j], stored to Xp[t][b][j] bf16.
// tile 128x128, K=512, BK=64, 4 waves each 64x64 (4x4 frags of 16x16x32).
__global__ __launch_bounds__(256) void k_xp(const u16* __restrict__ Xbf,
                                            const u16* __restrict__ Wxh,
                                            const float* __restrict__ bias,
                                            u16* __restrict__ Xp) {
  __shared__ u16 As[128 * 64];
  __shared__ u16 Bs[128 * 64];
  const int jt = blockIdx.x;   // 0..7   (N tiles)
  const int rt = blockIdx.y;   // 0..1023 (M tiles)
  const int tid = threadIdx.x;
  const int w = tid >> 6, l = tid & 63;
  const int mq = w & 1, nq = w >> 1;  // wave origin (mq*64, nq*64)
  f32x4 acc[4][4] = {};
  const u16* Ag = Xbf + rt * 128 * XD;
  const u16* Bg = Wxh + jt * 128 * XD;
  // staging map: inst idx covers rows idx*8+(l>>3), kk=(l&7)*8; LDS elem = idx*512 + l*8
  const int srow = (l >> 3), skk = (l & 7) * 8;
  for (int kc = 0; kc < 8; ++kc) {
    const int k0 = kc * 64;
    __syncthreads();
#pragma unroll
    for (int i = 0; i < 4; ++i) {
      int idx = w * 4 + i;
      int row = idx * 8 + srow;
      g2lds16(Ag + row * XD + k0 + skk, &As[idx * 512]);
      g2lds16(Bg + row * XD + k0 + skk, &Bs[idx * 512]);
    }
    asm volatile("s_waitcnt vmcnt(0)" ::: "memory");
    __syncthreads();
#pragma unroll
    for (int ks = 0; ks < 2; ++ks) {
      bf16x8 af[4], bv[4];
      const int kk = ks * 32 + (l >> 4) * 8;
#pragma unroll
      for (int am = 0; am < 4; ++am) {
        int row = mq * 64 + am * 16 + (l & 15);
        af[am] = *(const bf16x8*)&As[row * 64 + kk];
      }
#pragma unroll
      for (int bn = 0; bn < 4; ++bn) {
        int row = nq * 64 + bn * 16 + (l & 15);
        bv[bn] = *(const bf16x8*)&Bs[row * 64 + kk];
      }
#pragma unroll
      for (int am = 0; am < 4; ++am)
#pragma unroll
        for (int bn = 0; bn < 4; ++bn)
          acc[am][bn] = __builtin_amdgcn_mfma_f32_16x16x32_bf16(af[am], bv[bn],
                                                                acc[am][bn], 0, 0, 0);
    }
  }
  // epilogue: D row m=(l>>4)*4+reg (A-free dim), col n=l&15 (B-free dim)
#pragma unroll
  for (int bn = 0; bn < 4; ++bn) {
    int jg = jt * 128 + nq * 64 + bn * 16 + (l & 15);
    float bvf = bias[jg];
#pragma unroll
    for (int am = 0; am < 4; ++am)
#pragma unroll
      for (int r = 0; r < 4; ++r) {
        int m_in = mq * 64 + am * 16 + (l >> 4) * 4 + r;
        int rg = rt * 128 + m_in;
        int bidx = rg >> 8, tidx = rg & 255;  // r = b*256 + t
        Xp[(tidx * BATCH + bidx) * HD + jg] = f2bf(acc[am][bn][r] + bvf);
      }
  }
}

// --------------------------- H1 = sigmoid(Xp_0) -----------------------------
__global__ void k_h1(const u16* __restrict__ xp0, u16* __restrict__ h1) {
  int i = blockIdx.x * blockDim.x + threadIdx.x;  // 131072 threads, 4 elems each
  ushort4 x = ((const ushort4*)xp0)[i];
  ushort4 o;
  o.x = f2bf(sigmoidf(bf2f(x.x)));
  o.y = f2bf(sigmoidf(bf2f(x.y)));
  o.z = f2bf(sigmoidf(bf2f(x.z)));
  o.w = f2bf(sigmoidf(bf2f(x.w)));
  ((ushort4*)h1)[i] = o;
}

// --------------------------- recurrence step --------------------------------
// Hout[b][j] = sigmoid( sum_k Hin[b][k]*Whh[j][k] + xp_t[b][j] )
// grid (16 jt, 8 bi); block 256 thr = 4 waves (2x2 of 32x32); tile 64x64, BK=128.
__global__ __launch_bounds__(256) void k_step(const u16* __restrict__ Hin,
                                              u16* __restrict__ Hout,
                                              const u16* __restrict__ Whh,
                                              const u16* __restrict__ xp_t) {
  __shared__ u16 As[64 * 128];
  __shared__ u16 Bs[64 * 128];
  const int jt = blockIdx.x;  // 0..15
  const int bi = blockIdx.y;  // 0..7
  const int tid = threadIdx.x;
  const int w = tid >> 6, l = tid & 63;
  const int mh = w & 1, nh = w >> 1;  // wave origin (mh*32, nh*32)
  f32x4 acc[2][2] = {};
  const u16* Ag = Hin + bi * 64 * HD;
  const u16* Bg = Whh + jt * 64 * HD;
  // staging map: inst idx covers rows idx*4+(l>>4), kk=(l&15)*8; LDS elem = idx*512 + l*8
  const int srow = (l >> 4), skk = (l & 15) * 8;
  for (int kc = 0; kc < 8; ++kc) {
    const int k0 = kc * 128;
    __syncthreads();
#pragma unroll
    for (int i = 0; i < 4; ++i) {
      int idx = w * 4 + i;
      int row = idx * 4 + srow;
      g2lds16(Ag + row * HD + k0 + skk, &As[idx * 512]);
      g2lds16(Bg + row * HD + k0 + skk, &Bs[idx * 512]);
    }
    asm volatile("s_waitcnt vmcnt(0)" ::: "memory");
    __syncthreads();
#pragma unroll
    for (int ks = 0; ks < 4; ++ks) {
      const int kk = ks * 32 + (l >> 4) * 8;
      bf16x8 af[2], bv[2];
#pragma unroll
      for (int am = 0; am < 2; ++am) {
        int row = mh * 32 + am * 16 + (l & 15);
        af[am] = *(const bf16x8*)&As[row * 128 + kk];
      }
#pragma unroll
      for (int bn = 0; bn < 2; ++bn) {
        int row = nh * 32 + bn * 16 + (l & 15);
        bv[bn] = *(const bf16x8*)&Bs[row * 128 + kk];
      }
#pragma unroll
      for (int am = 0; am < 2; ++am)
#pragma unroll
        for (int bn = 0; bn < 2; ++bn)
          acc[am][bn] = __builtin_amdgcn_mfma_f32_16x16x32_bf16(af[am], bv[bn],
                                                                acc[am][bn], 0, 0, 0);
    }
  }
  // epilogue: add Xp, sigmoid, store bf16
#pragma unroll
  for (int am = 0; am < 2; ++am)
#pragma unroll
    for (int bn = 0; bn < 2; ++bn)
#pragma unroll
      for (int r = 0; r < 4; ++r) {
        int m = mh * 32 + am * 16 + (l >> 4) * 4 + r;
        int j = nh * 32 + bn * 16 + (l & 15);
        int brow = bi * 64 + m;
        int jcol = jt * 64 + j;
        float x = acc[am][bn][r] + bf2f(xp_t[brow * HD + jcol]);
        Hout[brow * HD + jcol] = f2bf(sigmoidf(x));
      }
}

// --------------------------- output ----------------------------------------
// out[b] = sum_k H[b][k]*v[k] + sum_j Xp255[b][j]*W_hy[j]
__global__ void k_out(const u16* __restrict__ H, const u16* __restrict__ xp,
                      const float* __restrict__ v, const float* __restrict__ why,
                      float* __restrict__ out) {
  int b = blockIdx.x;
  int tid = threadIdx.x;
  float s = 0.f;
  for (int k = tid; k < HD; k += 256) s += bf2f(H[b * HD + k]) * v[k];
  for (int j = tid; j < HD; j += 256) s += bf2f(xp[b * HD + j]) * why[j];
  __shared__ float red[256];
  red[tid] = s;
  __syncthreads();
  for (int off = 128; off > 0; off >>= 1) {
    if (tid < off) red[tid] += red[tid + off];
    __syncthreads();
  }
  if (tid == 0) out[b] = red[0];
}

// --------------------------- launch ----------------------------------------
extern "C" void kernel_launch(void* const* d_in, const int* in_sizes, int n_in,
                              void* d_out, int out_size, void* d_ws, size_t ws_size,
                              hipStream_t stream) {
  const float* X = (const float*)d_in[0];     // [512,256,512]
  const float* Whh = (const float*)d_in[1];   // [1024,1024]
  const float* Wxh = (const float*)d_in[2];   // [1024,512]
  const float* Why = (const float*)d_in[3];   // [1024]
  const float* bias = (const float*)d_in[4];  // [1024]
  float* out = (float*)d_out;                 // [512]

  char* ws = (char*)d_ws;
  // ws layout (bytes)
  u16* Xbf = (u16*)(ws + 0);                  // 134217728
  u16* Whh_bf = (u16*)(ws + 134217728);       // 2097152
  u16* Wxh_bf = (u16*)(ws + 136314880);       // 1048576
  float* v = (float*)(ws + 137363456);        // 4096
  u16* H0 = (u16*)(ws + 137367552);           // 1048576
  u16* H1 = (u16*)(ws + 138416128);           // 1048576
  u16* Xp = (u16*)(ws + 139464704);           // 268435456 (total 407900160)

  hipMemsetAsync(v, 0, 4096, stream);
  k_cvt<<<65536, 256, 0, stream>>>(X, Xbf, 16777216);    // 67108864/4
  k_cvt<<<1024, 256, 0, stream>>>(Whh, Whh_bf, 262144);  // 1048576/4
  k_cvt<<<512, 256, 0, stream>>>(Wxh, Wxh_bf, 131072);   // 524288/4
  k_v<<<dim3(4, 8), 256, 0, stream>>>(Whh, Why, v);
  k_xp<<<dim3(8, 1024), 256, 0, stream>>>(Xbf, Wxh_bf, bias, Xp);
  k_h1<<<512, 256, 0, stream>>>(Xp, H0);  // H_1 = sigmoid(Xp_0)

  u16* hb[2] = {H0, H1};
  for (int t = 1; t <= 254; ++t) {
    k_step<<<dim3(16, 8), 256, 0, stream>>>(hb[(t - 1) & 1], hb[t & 1], Whh_bf,
                                            Xp + (size_t)t * (BATCH * HD));
  }
  // H_255 is in hb[0] (t=254 writes hb[254&1]=hb[0])
  k_out<<<512, 256, 0, stream>>>(hb[0], Xp + (size_t)255 * (BATCH * HD), v, Why, out);
}